// Round 5
// baseline (206.288 us; speedup 1.0000x reference)
//
#include <hip/hip_runtime.h>
#include <hip/hip_bf16.h>

typedef short bf16x4 __attribute__((ext_vector_type(4)));
typedef short bf16x8 __attribute__((ext_vector_type(8)));
typedef float f32x4  __attribute__((ext_vector_type(4)));

#define LOG2E 1.4426950408889634f
#define QSCALE (0.125f * LOG2E)   // 1/sqrt(64) * log2(e), folded into Q

__device__ __forceinline__ short f2bf(float x) {
  union { __hip_bfloat16 h; short s; } u;
  u.h = __float2bfloat16(x);
  return u.s;
}

__device__ __forceinline__ float fast_exp2(float x) {
#if __has_builtin(__builtin_amdgcn_exp2f)
  return __builtin_amdgcn_exp2f(x);
#else
  return exp2f(x);
#endif
}

// global -> LDS direct copy, 16B per lane. LDS dest = uniform base + lane*16;
// global source address is PER-LANE (enables pre-swizzled source).
__device__ __forceinline__ void load16_lds(const void* g, void* l) {
#if __has_builtin(__builtin_amdgcn_global_load_lds)
  __builtin_amdgcn_global_load_lds(
      (const __attribute__((address_space(1))) unsigned int*)g,
      (__attribute__((address_space(3))) unsigned int*)l, 16, 0, 0);
#else
  const int lane = threadIdx.x & 63;
  *(bf16x8*)((char*)l + lane * 16) = *(const bf16x8*)((const char*)g + lane * 16);
#endif
}

// ---------------------------------------------------------------- x -> bf16
__global__ __launch_bounds__(256)
void cvt_x_kernel(const float* __restrict__ in, short* __restrict__ out, int n4) {
  for (int i = blockIdx.x * blockDim.x + threadIdx.x; i < n4; i += gridDim.x * blockDim.x) {
    const float4 v = ((const float4*)in)[i];
    bf16x4 o;
    o[0] = f2bf(v.x); o[1] = f2bf(v.y); o[2] = f2bf(v.z); o[3] = f2bf(v.w);
    ((bf16x4*)out)[i] = o;
  }
}

// ---------------------- all 4 weight transposes, one dispatch (grid 4096)
__global__ __launch_bounds__(256)
void trans_all_kernel(const float* __restrict__ Wq, const float* __restrict__ Wk,
                      const float* __restrict__ Wv, const float* __restrict__ Wo,
                      short* __restrict__ Wt3, short* __restrict__ Wot) {
  __shared__ float t[32][33];
  const int f = blockIdx.x;
  const float* in;
  short* out;
  int R, C, r0, c0;
  if (f < 3072) {
    const int which = f >> 10;           // 0=Wq 1=Wk 2=Wv
    const int rem = f & 1023;
    const int z = rem >> 6;              // head
    const int xy = rem & 63;             // 32 x-tiles * 2 y-tiles
    in = (which == 0 ? Wq : which == 1 ? Wk : Wv) + (size_t)z * 65536;
    out = Wt3 + (size_t)which * 1048576 + (size_t)z * 65536;
    R = 1024; C = 64; r0 = (xy >> 1) * 32; c0 = (xy & 1) * 32;
  } else {
    const int rem = f - 3072;
    in = Wo; out = Wot;
    R = 1024; C = 1024; r0 = (rem >> 5) * 32; c0 = (rem & 31) * 32;
  }
  const int tr = threadIdx.x >> 5, tc = threadIdx.x & 31;
#pragma unroll
  for (int p = 0; p < 4; ++p)
    t[tr + p * 8][tc] = in[(size_t)(r0 + tr + p * 8) * C + c0 + tc];
  __syncthreads();
#pragma unroll
  for (int p = 0; p < 4; ++p)
    out[(size_t)(c0 + tr + p * 8) * R + r0 + tc] = f2bf(t[tc][tr + p * 8]);
}

// ---------------------------------------------------------------- fused QKV GEMM
// C[4096][3072] = Xb[4096][1024] * Wt3[3072][1024]^T; 128x128 tile, 4 waves.
// Q/K blocks use SWAPPED-operand MFMA (C^T fragment: row<->n, col<->m) so the
// epilogue stores 8B bf16x4 along d. V blocks keep the unswapped orientation
// (col<->n) so [B,H,D,S] stores are 8B along s.
__global__ __launch_bounds__(256)
void gemm_qkv_kernel(const short* __restrict__ A, const short* __restrict__ Bt,
                     short* __restrict__ Qb, short* __restrict__ Kb,
                     short* __restrict__ Vt) {
  __shared__ short Al[128 * 32];
  __shared__ short Bl[128 * 32];
  const int tid = threadIdx.x;
  const int w = tid >> 6, lane = tid & 63;
  const int lq = lane & 15, lg = lane >> 4;
  const int m0 = blockIdx.x * 128, n0 = blockIdx.y * 128;
  const int which = n0 >> 10;  // 0=Q 1=K 2=V
  const int wr = (w >> 1) * 64, wc = (w & 1) * 64;

  f32x4 acc[4][4] = {};
  const int grow = lane >> 2;
  const int gcol = (lane & 3) * 8;

  for (int k0 = 0; k0 < 1024; k0 += 32) {
#pragma unroll
    for (int c = 0; c < 2; ++c) {
      const int chunk = (w << 1) | c;
      const int row = chunk * 16 + grow;
      load16_lds(A + (size_t)(m0 + row) * 1024 + k0 + gcol, &Al[chunk * 512]);
      load16_lds(Bt + (size_t)(n0 + row) * 1024 + k0 + gcol, &Bl[chunk * 512]);
    }
    __syncthreads();
    bf16x8 af[4], bfr[4];
#pragma unroll
    for (int i = 0; i < 4; ++i)
      af[i] = *(const bf16x8*)&Al[(wr + i * 16 + lq) * 32 + lg * 8];
#pragma unroll
    for (int j = 0; j < 4; ++j)
      bfr[j] = *(const bf16x8*)&Bl[(wc + j * 16 + lq) * 32 + lg * 8];
    if (which < 2) {
#pragma unroll
      for (int i = 0; i < 4; ++i)
#pragma unroll
        for (int j = 0; j < 4; ++j)
          acc[i][j] = __builtin_amdgcn_mfma_f32_16x16x32_bf16(bfr[j], af[i], acc[i][j], 0, 0, 0);
    } else {
#pragma unroll
      for (int i = 0; i < 4; ++i)
#pragma unroll
        for (int j = 0; j < 4; ++j)
          acc[i][j] = __builtin_amdgcn_mfma_f32_16x16x32_bf16(af[i], bfr[j], acc[i][j], 0, 0, 0);
    }
    __syncthreads();
  }

  if (which < 2) {
    // swapped: acc[i][j] row (lg*4+r) <-> n-sub of bfr[j], col lq <-> m-sub of af[i]
    short* Out = which ? Kb : Qb;
    const float sc = which ? 1.f : QSCALE;
    const int m = m0 + wr + lq;  // + i*16
#pragma unroll
    for (int i = 0; i < 4; ++i) {
      const int mm = m + i * 16;
      const int b = mm >> 11, s = mm & 2047;
#pragma unroll
      for (int j = 0; j < 4; ++j) {
        const int nn = (n0 + wc + j * 16 + lg * 4) & 1023;
        const int h = nn >> 6, d = nn & 63;
        bf16x4 o;
#pragma unroll
        for (int r = 0; r < 4; ++r) o[r] = f2bf(acc[i][j][r] * sc);
        *(bf16x4*)&Out[(size_t)((b * 16 + h) * 2048 + s) * 64 + d] = o;
      }
    }
  } else {
#pragma unroll
    for (int i = 0; i < 4; ++i) {
      const int mb = m0 + wr + i * 16 + lg * 4;
      const int b = mb >> 11, s = mb & 2047;
#pragma unroll
      for (int j = 0; j < 4; ++j) {
        const int nn = (n0 + wc + j * 16 + lq) & 1023;
        const int h = nn >> 6, d = nn & 63;
        bf16x4 o;
#pragma unroll
        for (int r = 0; r < 4; ++r) o[r] = f2bf(acc[i][j][r]);
        *(bf16x4*)&Vt[(size_t)((b * 16 + h) * 64 + d) * 2048 + s] = o;
      }
    }
  }
}

// ---------------------------------------------------------------- out-proj GEMM
// M-tile 64 x N-tile 128 -> grid (64,8) = 512 blocks (2/CU). Wave = 32m x 64n.
__global__ __launch_bounds__(256)
void gemm_out_kernel(const short* __restrict__ A, const short* __restrict__ Bt,
                     float* __restrict__ Out) {
  __shared__ short Al[64 * 32];
  __shared__ short Bl[128 * 32];
  const int tid = threadIdx.x;
  const int w = tid >> 6, lane = tid & 63;
  const int lq = lane & 15, lg = lane >> 4;
  const int m0 = blockIdx.x * 64, n0 = blockIdx.y * 128;
  const int wr = (w >> 1) * 32, wc = (w & 1) * 64;

  f32x4 acc[2][4] = {};
  const int grow = lane >> 2;
  const int gcol = (lane & 3) * 8;

  for (int k0 = 0; k0 < 1024; k0 += 32) {
    {
      const int arow = w * 16 + grow;
      load16_lds(A + (size_t)(m0 + arow) * 1024 + k0 + gcol, &Al[w * 512]);
#pragma unroll
      for (int c = 0; c < 2; ++c) {
        const int chunk = (w << 1) | c;
        const int row = chunk * 16 + grow;
        load16_lds(Bt + (size_t)(n0 + row) * 1024 + k0 + gcol, &Bl[chunk * 512]);
      }
    }
    __syncthreads();
    bf16x8 af[2], bfr[4];
#pragma unroll
    for (int i = 0; i < 2; ++i)
      af[i] = *(const bf16x8*)&Al[(wr + i * 16 + lq) * 32 + lg * 8];
#pragma unroll
    for (int j = 0; j < 4; ++j)
      bfr[j] = *(const bf16x8*)&Bl[(wc + j * 16 + lq) * 32 + lg * 8];
#pragma unroll
    for (int i = 0; i < 2; ++i)
#pragma unroll
      for (int j = 0; j < 4; ++j)
        acc[i][j] = __builtin_amdgcn_mfma_f32_16x16x32_bf16(af[i], bfr[j], acc[i][j], 0, 0, 0);
    __syncthreads();
  }

#pragma unroll
  for (int i = 0; i < 2; ++i)
#pragma unroll
    for (int r = 0; r < 4; ++r) {
      const int m = m0 + wr + i * 16 + lg * 4 + r;
      float* orow = Out + (size_t)m * 1024 + n0 + wc;
#pragma unroll
      for (int j = 0; j < 4; ++j) orow[j * 16 + lq] = acc[i][j][r];
    }
}

// ---------------------------------------------------------------- flash attention
// KEY-SPLIT + XCD-affinity: 1D grid 1024; bh=(l&7)*4+(l>>8), qt=(l>>3)&31 puts
// all 32 q-blocks of a head on one XCD (assuming XCD = linear%8 round-robin)
// -> K/V stage hits that XCD's L2. 4 waves; per 128-key tile each wave owns
// 32 keys x ALL 64 q. Fixed-reference softmax (shift-invariant; scores
// data-bounded) -> wave partials additive, merged once at the end. Staging via
// global_load_lds, XOR-swizzled per-lane SOURCE (linear LDS dest), same XOR on
// reads -> conflict-free. Gate/denom folded in (no separate kernel).
__global__ __launch_bounds__(256, 2)
void attn_kernel(const short* __restrict__ Qb, const short* __restrict__ Kb,
                 const short* __restrict__ Vt, const float* __restrict__ mask,
                 const float* __restrict__ gate, short* __restrict__ ctx) {
  __shared__ __align__(16) char lds[66560];
  // [0,16K) Kl0 | [16K,32K) Kl1 | [32K,48K) Vl0 | [48K,64K) Vl1
  // merge phase reuses [0,64K) as float[4][64 q][64 d] (swizzled); Lbuf @64K.

  const int tid = threadIdx.x;
  const int w = tid >> 6, lane = tid & 63;
  const int lq = lane & 15, lg = lane >> 4;
  const int l = blockIdx.x;
  const int bh = (l & 7) * 4 + (l >> 8);   // XCD-affinity decode (bijective)
  const int q0 = ((l >> 3) & 31) * 64;
  const int b = bh >> 4, h = bh & 15;
  const size_t bhoff = (size_t)bh * 2048 * 64;

  // gate scale (uniform scalar math, once per block)
  const float g = gate[h];
  const float eff = (g >= 1e-4f) ? g : 0.f;
  int active = 0;
#pragma unroll
  for (int j = 0; j < 16; ++j) active += (gate[j] > 1e-4f) ? 1 : 0;
  const float gsc = eff / fmaxf(1.f, (float)active / 16.f);

  // Q B-frags for all 64 q: qf[qt][half] = Q[q0+qt*16+lq][half*32 + lg*8 ..+7]
  bf16x8 qf[4][2];
#pragma unroll
  for (int qt = 0; qt < 4; ++qt) {
    const short* qp = Qb + bhoff + (size_t)(q0 + qt * 16 + lq) * 64 + lg * 8;
    qf[qt][0] = *(const bf16x8*)qp;
    qf[qt][1] = *(const bf16x8*)(qp + 32);
  }

  // staging lane constants (pre-swizzled global source offsets)
  const int koffs = (lane >> 3) * 128 + (((lane & 7) * 16) ^ ((lane >> 3) << 4));
  const int vrowc = lane >> 4;
  const int vs_e = ((lane & 15) * 16) ^ (vrowc << 4);
  const int vs_o = ((lane & 15) * 16) ^ ((vrowc + 4) << 4);
  const char* KbB = (const char*)(Kb + bhoff);
  const char* VtB = (const char*)(Vt + bhoff);

  // read-side constants
  const int sw = (lq & 7) << 4;
  const int kcol0 = (lg * 16) ^ sw, kcol1 = (64 + lg * 16) ^ sw;
  const int vcol0 = (w * 64 + lg * 8) ^ sw, vcol1 = (w * 64 + 32 + lg * 8) ^ sw;
  const float* maskp = mask + b * 2048;

  f32x4 acc[4][4] = {};  // [dt][qt]: O_partial[d=dt*16+lg*4+r][q=qt*16+lq]
  f32x4 lacc[4] = {};    // [qt] partial sum of p

#define STAGE(T, P)                                                              \
  {                                                                              \
    char* kd = lds + (P)*16384 + w * 4096;                                       \
    const char* ks = KbB + (size_t)((T)*128 + w * 32) * 128 + koffs;             \
    char* vd = lds + 32768 + (P)*16384 + w * 4096;                               \
    const char* vsb = VtB + (size_t)(w * 16 + vrowc) * 4096 + (T)*256;           \
    load16_lds(ks, kd);                                                          \
    load16_lds(ks + 1024, kd + 1024);                                            \
    load16_lds(ks + 2048, kd + 2048);                                            \
    load16_lds(ks + 3072, kd + 3072);                                            \
    load16_lds(vsb + vs_e, vd);                                                  \
    load16_lds(vsb + 16384 + vs_o, vd + 1024);                                   \
    load16_lds(vsb + 32768 + vs_e, vd + 2048);                                   \
    load16_lds(vsb + 49152 + vs_o, vd + 3072);                                   \
  }

  STAGE(0, 0);
  __syncthreads();

  for (int t = 0; t < 16; ++t) {
    const int cur = t & 1;
    const f32x4 mk0 = *(const f32x4*)(maskp + t * 128 + w * 32 + lg * 4);
    const f32x4 mk1 = *(const f32x4*)(maskp + t * 128 + w * 32 + 16 + lg * 4);
    if (t < 15) STAGE(t + 1, cur ^ 1);

    // ---- scores: key = t*128 + w*32 + kt*16 + lg*4 + r, q = qt*16 + lq
    const char* Kc = lds + cur * 16384 + (w * 32 + lq) * 128;
    f32x4 s[2][4];
#pragma unroll
    for (int kt = 0; kt < 2; ++kt) {
      const bf16x8 ka0 = *(const bf16x8*)(Kc + kt * 2048 + kcol0);
      const bf16x8 ka1 = *(const bf16x8*)(Kc + kt * 2048 + kcol1);
#pragma unroll
      for (int qt = 0; qt < 4; ++qt) {
        f32x4 ts = {};
        ts = __builtin_amdgcn_mfma_f32_16x16x32_bf16(ka0, qf[qt][0], ts, 0, 0, 0);
        ts = __builtin_amdgcn_mfma_f32_16x16x32_bf16(ka1, qf[qt][1], ts, 0, 0, 0);
        s[kt][qt] = ts;
      }
    }

    // ---- fixed-ref softmax: p = exp2(s + m*log2e)
    bf16x4 pf[2][4];
#pragma unroll
    for (int kt = 0; kt < 2; ++kt) {
      const f32x4 mkv = kt ? mk1 : mk0;
#pragma unroll
      for (int qt = 0; qt < 4; ++qt) {
        const float p0 = fast_exp2(fmaf(mkv[0], LOG2E, s[kt][qt][0]));
        const float p1 = fast_exp2(fmaf(mkv[1], LOG2E, s[kt][qt][1]));
        const float p2 = fast_exp2(fmaf(mkv[2], LOG2E, s[kt][qt][2]));
        const float p3 = fast_exp2(fmaf(mkv[3], LOG2E, s[kt][qt][3]));
        pf[kt][qt][0] = f2bf(p0); pf[kt][qt][1] = f2bf(p1);
        pf[kt][qt][2] = f2bf(p2); pf[kt][qt][3] = f2bf(p3);
        const f32x4 pv = {p0, p1, p2, p3};
        lacc[qt] += pv;
      }
    }

    // ---- PV at K=32, key-permuted fragments
    bf16x8 pb[4];
#pragma unroll
    for (int qt = 0; qt < 4; ++qt)
      pb[qt] = __builtin_shufflevector(pf[0][qt], pf[1][qt], 0, 1, 2, 3, 4, 5, 6, 7);
#pragma unroll
    for (int dt = 0; dt < 4; ++dt) {
      const char* Vrow = lds + 32768 + cur * 16384 + (dt * 16 + lq) * 256;
      const bf16x4 v0 = *(const bf16x4*)(Vrow + vcol0);
      const bf16x4 v1 = *(const bf16x4*)(Vrow + vcol1);
      const bf16x8 av = __builtin_shufflevector(v0, v1, 0, 1, 2, 3, 4, 5, 6, 7);
#pragma unroll
      for (int qt = 0; qt < 4; ++qt)
        acc[dt][qt] = __builtin_amdgcn_mfma_f32_16x16x32_bf16(av, pb[qt], acc[dt][qt], 0, 0, 0);
    }

    __syncthreads();
  }
#undef STAGE

  // ---- merge: partials -> LDS float[w][q][d] (row 256B, XOR-swizzled)
#pragma unroll
  for (int dt = 0; dt < 4; ++dt)
#pragma unroll
    for (int qt = 0; qt < 4; ++qt)
      *(f32x4*)(lds + w * 16384 + (qt * 16 + lq) * 256 + ((dt * 64 + lg * 16) ^ sw)) =
          acc[dt][qt];

  // per-wave l partials: reduce with ALL lanes active, guard only the store
  float* Lb = (float*)(lds + 65536);
#pragma unroll
  for (int qt = 0; qt < 4; ++qt) {
    float lt = (lacc[qt][0] + lacc[qt][1]) + (lacc[qt][2] + lacc[qt][3]);
    lt += __shfl_xor(lt, 16);
    lt += __shfl_xor(lt, 32);
    if (lg == 0) Lb[w * 64 + qt * 16 + lq] = lt;
  }
  __syncthreads();

  // this wave finalizes q-rows w*16 + lq
  const float lsum = Lb[w * 16 + lq] + Lb[64 + w * 16 + lq] +
                     Lb[128 + w * 16 + lq] + Lb[192 + w * 16 + lq];
  const float osc = gsc / lsum;
  const int qabs = q0 + w * 16 + lq;
#pragma unroll
  for (int dt = 0; dt < 4; ++dt) {
    const int dby = (dt * 64 + lg * 16) ^ sw;
    f32x4 o = *(const f32x4*)(lds + (w * 16 + lq) * 256 + dby);
    o += *(const f32x4*)(lds + 16384 + (w * 16 + lq) * 256 + dby);
    o += *(const f32x4*)(lds + 32768 + (w * 16 + lq) * 256 + dby);
    o += *(const f32x4*)(lds + 49152 + (w * 16 + lq) * 256 + dby);
    bf16x4 ob;
#pragma unroll
    for (int r = 0; r < 4; ++r) ob[r] = f2bf(o[r] * osc);
    *(bf16x4*)&ctx[(size_t)(b * 2048 + qabs) * 1024 + h * 64 + dt * 16 + lg * 4] = ob;
  }
}

// ---------------------------------------------------------------- launch
extern "C" void kernel_launch(void* const* d_in, const int* in_sizes, int n_in,
                              void* d_out, int out_size, void* d_ws, size_t ws_size,
                              hipStream_t stream) {
  (void)in_sizes; (void)n_in; (void)out_size; (void)ws_size;
  const float* x    = (const float*)d_in[0];
  const float* mask = (const float*)d_in[1];
  const float* Wq   = (const float*)d_in[2];
  const float* Wk   = (const float*)d_in[3];
  const float* Wv   = (const float*)d_in[4];
  const float* Wo   = (const float*)d_in[5];
  const float* gate = (const float*)d_in[6];
  float* out = (float*)d_out;

  char* ws = (char*)d_ws;
  const size_t MB = 1024 * 1024;
  short* Xb  = (short*)(ws + 256);             // 8 MB  [4096][1024]
  short* Wt3 = (short*)(ws + 256 + 8 * MB);    // 6 MB  stacked Q,K,V transposed
  short* Wot = (short*)(ws + 256 + 14 * MB);   // 2 MB  [1024][1024]
  short* Qb  = (short*)(ws + 256 + 16 * MB);   // 8 MB  [B,H,S,D] pre-scaled
  short* Kb  = (short*)(ws + 256 + 24 * MB);   // 8 MB  [B,H,S,D]
  short* Vt  = (short*)(ws + 256 + 32 * MB);   // 8 MB  [B,H,D,S]
  short* ctx = (short*)(ws + 256 + 40 * MB);   // 8 MB  [4096][1024] gate-scaled

  cvt_x_kernel<<<2048, 256, 0, stream>>>(x, Xb, 4194304 / 4);
  trans_all_kernel<<<4096, 256, 0, stream>>>(Wq, Wk, Wv, Wo, Wt3, Wot);
  gemm_qkv_kernel<<<dim3(32, 24), 256, 0, stream>>>(Xb, Wt3, Qb, Kb, Vt);
  attn_kernel<<<1024, 256, 0, stream>>>(Qb, Kb, Vt, mask, gate, ctx);
  gemm_out_kernel<<<dim3(64, 8), 256, 0, stream>>>(ctx, Wot, out);
}